// Round 1
// baseline (621.397 us; speedup 1.0000x reference)
//
#include <hip/hip_runtime.h>

// Izhikevich neuron scan: 16384 independent (batch, neuron) chains, each
// sequential over 2000 steps. Memory-bound: 131 MB in + 393 MB out.
// One thread per chain; blocks of 64 -> grid 256 -> 1 wave per CU.
// P-deep register prefetch pipeline hides HBM load latency.
//
// NUMERICS: must match numpy fp32 op-for-op (spike-threshold flips cost
// O(100) absmax vs 1.48 threshold). fp contract OFF, exact expression order.

#define NSTEPS 2000
#define NNEUR  512
#define BATCH  32
#define PLANE  ((size_t)BATCH * NSTEPS * NNEUR)   // 32,768,000
#define PF     8                                   // prefetch depth

__device__ __forceinline__ void izh_step(float i_t, float& v, float& u, float& s) {
#pragma clang fp contract(off)
    // dv = (0.04*v*v + 5.0*v + 140.0 - u + i_t) * DT   (DT = 0.5)
    float t1 = 0.04f * v;
    t1 = t1 * v;
    float t2 = 5.0f * v;
    float acc = t1 + t2;
    acc = acc + 140.0f;
    acc = acc - u;
    acc = acc + i_t;
    float dv = acc * 0.5f;
    // du = A*(B*v - u)*DT = (0.02*(0.2*v - u))*0.5  -- uses OLD v
    float t4 = 0.2f * v;
    t4 = t4 - u;
    t4 = 0.02f * t4;
    float du = t4 * 0.5f;
    v = v + dv;
    u = u + du;
    bool sp = (v >= 30.0f);
    s = sp ? 1.0f : 0.0f;
    // v = v*(1-s) + C*s  -> exact select for s in {0,1}
    v = sp ? -65.0f : v;
    // u = u + D*s        -> exact select
    u = sp ? (u + 8.0f) : u;
}

__global__ __launch_bounds__(64, 1) void izh_kernel(const float* __restrict__ in,
                                                    float* __restrict__ out) {
    const int gid = blockIdx.x * 64 + threadIdx.x;    // [0, 16384)
    const int b = gid >> 9;                            // batch
    const int n = gid & (NNEUR - 1);                   // neuron

    const float* ip = in + (size_t)b * ((size_t)NSTEPS * NNEUR) + n;
    float* os = out + (size_t)b * ((size_t)NSTEPS * NNEUR) + n;  // spikes
    float* ov = os + PLANE;                                       // voltages
    float* ou = ov + PLANE;                                       // recovery

    float v = -65.0f;
    float u = -13.0f;   // B*C = 0.2 * -65.0 = -13 exactly

    float buf[PF];
#pragma unroll
    for (int k = 0; k < PF; ++k)
        buf[k] = ip[(size_t)k * NNEUR];

    // main blocks with prefetch (all but the last PF steps)
    for (int blk = 0; blk < NSTEPS / PF - 1; ++blk) {
        const int t0 = blk * PF;
#pragma unroll
        for (int k = 0; k < PF; ++k) {
            float i_t = buf[k];
            buf[k] = ip[(size_t)(t0 + k + PF) * NNEUR];   // prefetch step t+PF
            float s;
            izh_step(i_t, v, u, s);
            const size_t off = (size_t)(t0 + k) * NNEUR;
            os[off] = s;
            ov[off] = v;
            ou[off] = u;
        }
    }
    // tail block, no prefetch
    {
        const int t0 = NSTEPS - PF;
#pragma unroll
        for (int k = 0; k < PF; ++k) {
            float i_t = buf[k];
            float s;
            izh_step(i_t, v, u, s);
            const size_t off = (size_t)(t0 + k) * NNEUR;
            os[off] = s;
            ov[off] = v;
            ou[off] = u;
        }
    }
}

extern "C" void kernel_launch(void* const* d_in, const int* in_sizes, int n_in,
                              void* d_out, int out_size, void* d_ws, size_t ws_size,
                              hipStream_t stream) {
    const float* in = (const float*)d_in[0];
    float* out = (float*)d_out;
    const int threads = BATCH * NNEUR;   // 16384
    izh_kernel<<<threads / 64, 64, 0, stream>>>(in, out);
}

// Round 2
// 525.121 us; speedup vs baseline: 1.1833x; 1.1833x over previous
//
#include <hip/hip_runtime.h>

// Izhikevich neuron scan: 16384 independent chains x 2000 sequential steps.
// R1 post-mortem: 268us, 1.7TB/s, VALUBusy 6.9% -- latency-bound. 1 wave/CU
// (structural: 256 waves total), and the 8-deep register prefetch shares one
// in-order vmcnt queue with 3 stores/step => step time settles at L_eff/8.
//
// R2: stage input through LDS in 100-step chunks via global_load_lds(16B):
// one instruction stages 4 steps x 64 neurons (lane L -> step L>>4, neurons
// (L&15)*4..+3, LDS step-major). Double-buffered; ONE s_waitcnt vmcnt(0) per
// chunk. Within a chunk: ds_read (group-ahead reg prefetch) + compute +
// fire-and-forget stores -- no vmem waits. Single wave/block => no barrier.
//
// NUMERICS: exact numpy op order, fp contract off (spike flips cost O(100)).

#define NSTEPS 2000
#define NNEUR  512
#define BATCH  32
#define INPLANE 1024000u                       // NSTEPS*NNEUR per batch
#define PLANE  32768000u                       // BATCH*NSTEPS*NNEUR per out plane
#define CHUNK  100
#define NCHUNK (NSTEPS / CHUNK)                // 20
#define NG     (CHUNK / 4)                     // 25 groups of 4 steps

typedef const __attribute__((address_space(1))) unsigned GPtr;
typedef __attribute__((address_space(3))) unsigned LPtr;

__device__ __forceinline__ void izh_step(float i_t, float& v, float& u, float& s) {
#pragma clang fp contract(off)
    float t1 = 0.04f * v;
    t1 = t1 * v;
    float t2 = 5.0f * v;
    float acc = t1 + t2;
    acc = acc + 140.0f;
    acc = acc - u;
    acc = acc + i_t;
    float dv = acc * 0.5f;
    float t4 = 0.2f * v;
    t4 = t4 - u;
    t4 = 0.02f * t4;
    float du = t4 * 0.5f;
    v = v + dv;
    u = u + du;
    bool sp = (v >= 30.0f);
    s = sp ? 1.0f : 0.0f;
    v = sp ? -65.0f : v;
    u = sp ? (u + 8.0f) : u;
}

__global__ __launch_bounds__(64, 1) void izh_kernel(const float* __restrict__ in,
                                                    float* __restrict__ out) {
    __shared__ float lds[2][CHUNK * 64];       // 2 x 25.6 KB

    const int lane = threadIdx.x;
    const int gid  = blockIdx.x * 64 + lane;
    const unsigned b  = (unsigned)(gid >> 9);            // batch (uniform per block)
    const unsigned n  = (unsigned)(gid & (NNEUR - 1));   // this lane's neuron
    const unsigned n0 = (unsigned)((blockIdx.x * 64) & (NNEUR - 1)); // block's neuron base

    // Per-lane global source for staging: lane L covers step (L>>4), 16B at
    // neurons n0 + (L&15)*4. One global_load_lds(16) stages 4 steps.
    const float* gsrc = in + (size_t)b * INPLANE
                           + (size_t)(lane >> 4) * NNEUR
                           + n0 + (size_t)(lane & 15) * 4;

    unsigned voff = b * INPLANE + n;           // element offset in each out plane

    float v = -65.0f;
    float u = -13.0f;                          // B*C exactly

    // stage chunk 0 into lds[0]
#pragma unroll
    for (int g = 0; g < NG; ++g) {
        __builtin_amdgcn_global_load_lds((GPtr*)(gsrc + (size_t)(4 * g) * NNEUR),
                                         (LPtr*)&lds[0][g * 256], 16, 0, 0);
    }

    for (int c = 0; c < NCHUNK; ++c) {
        // chunk c's staged data must be resident before ds_reads
        asm volatile("s_waitcnt vmcnt(0)" ::: "memory");

        // kick off staging of chunk c+1 into the other buffer
        if (c + 1 < NCHUNK) {
            const float* gs = gsrc + (size_t)(c + 1) * CHUNK * NNEUR;
            float* lb = &lds[(c + 1) & 1][0];
#pragma unroll
            for (int g = 0; g < NG; ++g) {
                __builtin_amdgcn_global_load_lds((GPtr*)(gs + (size_t)(4 * g) * NNEUR),
                                                 (LPtr*)(lb + g * 256), 16, 0, 0);
            }
        }

        const float* lbuf = &lds[c & 1][0];
        float ra[4], rb[4];
#pragma unroll
        for (int j = 0; j < 4; ++j) ra[j] = lbuf[j * 64 + lane];

        for (int g = 0; g < NG - 1; g += 2) {
            // prefetch group g+1 while computing group g
#pragma unroll
            for (int j = 0; j < 4; ++j) rb[j] = lbuf[(4 * (g + 1) + j) * 64 + lane];
#pragma unroll
            for (int j = 0; j < 4; ++j) {
                float s;
                izh_step(ra[j], v, u, s);
                out[voff] = s;
                out[voff + PLANE] = v;
                out[voff + 2u * PLANE] = u;
                voff += NNEUR;
            }
            if (g + 2 < NG) {
#pragma unroll
                for (int j = 0; j < 4; ++j) ra[j] = lbuf[(4 * (g + 2) + j) * 64 + lane];
            }
#pragma unroll
            for (int j = 0; j < 4; ++j) {
                float s;
                izh_step(rb[j], v, u, s);
                out[voff] = s;
                out[voff + PLANE] = v;
                out[voff + 2u * PLANE] = u;
                voff += NNEUR;
            }
        }
        // tail group NG-1 (NG odd), already in ra
#pragma unroll
        for (int j = 0; j < 4; ++j) {
            float s;
            izh_step(ra[j], v, u, s);
            out[voff] = s;
            out[voff + PLANE] = v;
            out[voff + 2u * PLANE] = u;
            voff += NNEUR;
        }
    }
}

extern "C" void kernel_launch(void* const* d_in, const int* in_sizes, int n_in,
                              void* d_out, int out_size, void* d_ws, size_t ws_size,
                              hipStream_t stream) {
    const float* in = (const float*)d_in[0];
    float* out = (float*)d_out;
    izh_kernel<<<(BATCH * NNEUR) / 64, 64, 0, stream>>>(in, out);
}